// Round 6
// baseline (95.656 us; speedup 1.0000x reference)
//
#include <hip/hip_runtime.h>

// GaussianHistogram: hist[b,i,j] = sum_n exp(-pi*(u1-i)^2) * exp(-pi*(u2-j)^2) * mask
// u = (x - MIN_V)/DELTA - 0.5 ; COEF == 1.0 exactly.
//
// v7: SINGLE-PASS GLOBAL SCATTER. v1-v6 falsified every linear model (evals/CU
// varied 4x, DS lane-ops 3x, time moved <15%); the invariant was the broadcast
// ownership structure (every block scans all/chunk points, discards most taps).
// v7 processes each point EXACTLY ONCE (262144 evals total, 16x less than v6)
// and scatters 3 packed u64 taps per point straight to a 2 MB workspace with
// device-scope global atomics (memory-side, coherent across XCDs; inter-kernel
// visibility via stream ordering):
//   zero_ws (2 MB) -> scatter (786K global_atomic_add_x2) -> unpack (ws->out).
//
// Packing (identical math to v5/v6, both passed absmax 0.0156): per point,
// 3 exact row taps x one 4-column 16-bit-field u64 word. Two phase-shifted
// packings (phase0 words cover cols 4w.., phase1 cols 4w+2..) so the 3-tap col
// window [j0-1,j0+1] always fits one word (4th field = exact bonus tap, dist
// <=2.5; reference sums all cols so extra taps only reduce truncation).
// Dropped taps >=1.5 bins, weight <= 8.5e-4. Fields .10 fixed point; per-field
// mass <= Poisson(lam~4.5) tail << 64.0 field cap -> no cross-field carry.
//
// ws layout: u64 ws[b][phase][row 256][word 64] = 262144 u64 = 2 MB.

#define BINS   256
#define NPTS   32768
#define BATCH  8
#define WORDS  64                       // u64 words per row per phase
#define WSU64  (BATCH * 2 * BINS * WORDS)  // 262144

static constexpr float kInvDelta = 256.0f / 1.5f;                  // 1/DELTA
static constexpr float kUAdd     = 0.25f * (256.0f / 1.5f) - 0.5f; // (x-MIN)/D - 0.5
static constexpr float kPi       = 3.14159265358979323846f;
static constexpr float kFix      = 1024.0f;                        // .10 fixed point
static constexpr float kInvFix   = 1.0f / 1024.0f;

__global__ __launch_bounds__(1024) void gh_zero(unsigned long long* __restrict__ ws)
{
    ws[blockIdx.x * 1024 + threadIdx.x] = 0ULL;   // 256 blocks x 1024 = WSU64
}

__global__ __launch_bounds__(256) void gh_scatter(
    const float* __restrict__ x1, const float* __restrict__ x2,
    const float* __restrict__ mask, unsigned long long* __restrict__ ws)
{
    const int g  = blockIdx.x * 256 + threadIdx.x;   // float4 id, 65536 total
    const int b  = g >> 13;                          // 8192 float4 per batch
    const int n4 = g & 8191;

    const float4 a4 = ((const float4*)(x1   + b * NPTS))[n4];
    const float4 b4 = ((const float4*)(x2   + b * NPTS))[n4];
    const float4 m4 = ((const float4*)(mask + b * NPTS))[n4];

    const float pv1[4] = {a4.x, a4.y, a4.z, a4.w};
    const float pv2[4] = {b4.x, b4.y, b4.z, b4.w};
    const float pm[4]  = {m4.x, m4.y, m4.z, m4.w};

    unsigned long long* WB = ws + (size_t)b * (2 * BINS * WORDS);

#pragma unroll
    for (int k = 0; k < 4; ++k) {
        const float u1 = fmaf(pv1[k], kInvDelta, kUAdd);
        const float u2 = fmaf(pv2[k], kInvDelta, kUAdd);
        const float fi = rintf(u1);
        int i0 = (int)fi;
        i0 = min(254, max(1, i0));            // memory-safety (no-op in-spec)
        const float t1 = u1 - fi;             // in [-0.5, 0.5]

        // even window start containing cols [j0-1, j0+1] in 4 cols
        int e = (((int)rintf(u2)) - 1) & ~1;
        e = min(250, max(0, e));              // memory-safety (no-op in-spec)
        const int  ph   = (e >> 1) & 1;       // phase: which packing
        const int  word = e >> 2;             // same formula both phases
        const float t2  = u2 - (float)e;      // offset of u2 from col e

        // 3 exact row weights
        float w1a[3];
#pragma unroll
        for (int a = 0; a < 3; ++a) {
            const float d = t1 - (float)(a - 1);
            w1a[a] = __expf(-kPi * d * d);
        }
        // 4 exact col-field weights (mask + fixed scale folded in)
        float W2[4];
#pragma unroll
        for (int c = 0; c < 4; ++c) {
            const float d = t2 - (float)c;
            W2[c] = __expf(-kPi * d * d) * (pm[k] * kFix);
        }

        unsigned long long* P = WB + (size_t)ph * (BINS * WORDS) + word;
#pragma unroll
        for (int a = 0; a < 3; ++a) {
            const int r = i0 - 1 + a;
            const float wa = w1a[a];
            const unsigned f0 = (unsigned)fmaf(wa, W2[0], 0.5f);
            const unsigned f1 = (unsigned)fmaf(wa, W2[1], 0.5f);
            const unsigned f2 = (unsigned)fmaf(wa, W2[2], 0.5f);
            const unsigned f3 = (unsigned)fmaf(wa, W2[3], 0.5f);
            const unsigned long long w =
                (unsigned long long)(f0 | (f1 << 16)) |
                ((unsigned long long)(f2 | (f3 << 16)) << 32);
            atomicAdd(&P[(size_t)r * WORDS], w);   // global_atomic_add_x2, no return
        }
    }
}

// out[b,r,c] = (phase0 field + phase1 field) / 1024
__global__ __launch_bounds__(1024) void gh_unpack(
    const unsigned long long* __restrict__ ws, float* __restrict__ out)
{
    const int g     = blockIdx.x * 1024 + threadIdx.x;  // float2 id, 262144 total
    const int cell0 = g * 2;
    const int b     = cell0 >> 16;
    const int rem   = cell0 & 65535;
    const int r     = rem >> 8;
    const int c0    = rem & 255;          // even

    const unsigned long long* WB = ws + (size_t)b * (2 * BINS * WORDS);
    const unsigned long long we = WB[(size_t)r * WORDS + (c0 >> 2)];
    unsigned a0 = (unsigned)(we >> (16 * (c0 & 3)))       & 0xFFFFu;
    unsigned a1 = (unsigned)(we >> (16 * ((c0 + 1) & 3))) & 0xFFFFu;  // same word
    if (c0 >= 2) {
        const unsigned long long wo =
            WB[(size_t)(BINS * WORDS) + r * WORDS + ((c0 - 2) >> 2)];
        a0 += (unsigned)(wo >> (16 * ((c0 - 2) & 3))) & 0xFFFFu;
        a1 += (unsigned)(wo >> (16 * ((c0 - 1) & 3))) & 0xFFFFu;      // same word
    }
    float2 f;
    f.x = (float)a0 * kInvFix;
    f.y = (float)a1 * kInvFix;
    *(float2*)(out + (size_t)cell0) = f;
}

extern "C" void kernel_launch(void* const* d_in, const int* in_sizes, int n_in,
                              void* d_out, int out_size, void* d_ws, size_t ws_size,
                              hipStream_t stream) {
    const float* x1   = (const float*)d_in[0];
    const float* x2   = (const float*)d_in[1];
    const float* mask = (const float*)d_in[2];
    float*       out  = (float*)d_out;
    unsigned long long* ws = (unsigned long long*)d_ws;

    gh_zero   <<<dim3(WSU64 / 1024), 1024, 0, stream>>>(ws);
    gh_scatter<<<dim3(BATCH * NPTS / 4 / 256), 256, 0, stream>>>(x1, x2, mask, ws);
    gh_unpack <<<dim3(BATCH * BINS * BINS / 2048), 1024, 0, stream>>>(ws, out);
}